// Round 1
// baseline (7037.893 us; speedup 1.0000x reference)
//
#include <hip/hip_runtime.h>
#include <hip/hip_bf16.h>

// Dimensions (fixed by the problem)
#define T_STEPS 128
#define D_IN    300
#define H_DIM   100
#define KDIM    400   // D + H
#define G4      400   // 4*H
#define ROWS    16    // batch rows per block
#define XH_PAD  20    // padded inner dim for xh[k][r] layout (16B-aligned rows, breaks bank conflicts)
#define BLOCK   512

__device__ __forceinline__ float sigmoidf_(float x) {
    return 1.0f / (1.0f + __expf(-x));
}
__device__ __forceinline__ float tanh_fast(float x) {
    // tanh(x) = 2*sigmoid(2x) - 1
    return 2.0f / (1.0f + __expf(-2.0f * x)) - 1.0f;
}

__global__ __launch_bounds__(BLOCK) void lstm_fused_f32(
    const float* __restrict__ premises,
    const float* __restrict__ hypotheses,
    const float* __restrict__ W0, const float* __restrict__ b0,
    const float* __restrict__ W1, const float* __restrict__ b1,
    const float* __restrict__ W2, const float* __restrict__ b2,
    const float* __restrict__ W3, const float* __restrict__ b3,
    float* __restrict__ out)
{
    // LDS: 32000 + 25600 + 6400 = 64000 B (fits 64KB static limit)
    __shared__ float xh[KDIM * XH_PAD];     // [k][r]: k in 0..399 (0..299 = x_t, 300..399 = h)
    __shared__ float z_lds[ROWS * G4];      // [r][g]
    __shared__ float c_lds[ROWS * H_DIM];   // [r][g]

    const int tid   = threadIdx.x;
    const int combo = blockIdx.y;           // 0: p-fw, 1: p-bw, 2: h-fw, 3: h-bw
    const int row0  = blockIdx.x * ROWS;

    const float* x = (combo < 2) ? premises : hypotheses;
    const float* W;
    const float* bias;
    switch (combo) {
        case 0:  W = W0; bias = b0; break;
        case 1:  W = W1; bias = b1; break;
        case 2:  W = W2; bias = b2; break;
        default: W = W3; bias = b3; break;
    }
    const bool backward = (combo & 1) != 0;

    // zero-init c and h
    for (int i = tid; i < ROWS * H_DIM; i += BLOCK) c_lds[i] = 0.0f;
    for (int i = tid; i < H_DIM * XH_PAD; i += BLOCK) xh[D_IN * XH_PAD + i] = 0.0f;

    const bool active = (tid < 400);
    const int gg = tid % 100;   // gate group -> g0 = gg*4
    const int rg = tid / 100;   // row group  -> r0 = rg*4   (valid when active)
    const int g0 = gg * 4;
    const int r0 = rg * 4;

    float bias4[4] = {0.f, 0.f, 0.f, 0.f};
    if (active) {
        bias4[0] = bias[g0 + 0];
        bias4[1] = bias[g0 + 1];
        bias4[2] = bias[g0 + 2];
        bias4[3] = bias[g0 + 3];
    }

    for (int t = 0; t < T_STEPS; ++t) {
        const int tt = backward ? (T_STEPS - 1 - t) : t;

        // ---- stage x_t into xh[0..299][r] (transposed, coalesced global reads) ----
        for (int i = tid; i < ROWS * D_IN; i += BLOCK) {
            const int r = i / D_IN;
            const int d = i - r * D_IN;
            xh[d * XH_PAD + r] = x[((row0 + r) * T_STEPS + tt) * D_IN + d];
        }
        __syncthreads();

        // ---- z[r][g] = [x_t, h] @ W + b, each thread does a 4x4 tile ----
        if (active) {
            float acc[4][4];
            #pragma unroll
            for (int rr = 0; rr < 4; ++rr)
                #pragma unroll
                for (int j = 0; j < 4; ++j)
                    acc[rr][j] = bias4[j];

            #pragma unroll 8
            for (int k = 0; k < KDIM; ++k) {
                const float4 xv = *reinterpret_cast<const float4*>(&xh[k * XH_PAD + r0]);
                const float4 wv = *reinterpret_cast<const float4*>(&W[k * G4 + g0]);
                acc[0][0] += xv.x * wv.x; acc[0][1] += xv.x * wv.y;
                acc[0][2] += xv.x * wv.z; acc[0][3] += xv.x * wv.w;
                acc[1][0] += xv.y * wv.x; acc[1][1] += xv.y * wv.y;
                acc[1][2] += xv.y * wv.z; acc[1][3] += xv.y * wv.w;
                acc[2][0] += xv.z * wv.x; acc[2][1] += xv.z * wv.y;
                acc[2][2] += xv.z * wv.z; acc[2][3] += xv.z * wv.w;
                acc[3][0] += xv.w * wv.x; acc[3][1] += xv.w * wv.y;
                acc[3][2] += xv.w * wv.z; acc[3][3] += xv.w * wv.w;
            }
            #pragma unroll
            for (int rr = 0; rr < 4; ++rr) {
                *reinterpret_cast<float4*>(&z_lds[(r0 + rr) * G4 + g0]) =
                    make_float4(acc[rr][0], acc[rr][1], acc[rr][2], acc[rr][3]);
            }
        }
        __syncthreads();

        // ---- gate nonlinearities; update c (LDS) and h (back into xh) ----
        if (tid < H_DIM) {
            const int g = tid;
            #pragma unroll
            for (int r = 0; r < ROWS; ++r) {
                const float iv = z_lds[r * G4 + g];
                const float jv = z_lds[r * G4 + g + 100];
                const float fv = z_lds[r * G4 + g + 200];
                const float ov = z_lds[r * G4 + g + 300];
                const float c  = c_lds[r * H_DIM + g];
                const float c2 = c * sigmoidf_(fv + 1.0f) + sigmoidf_(iv) * tanh_fast(jv);
                const float h2 = tanh_fast(c2) * sigmoidf_(ov);
                c_lds[r * H_DIM + g] = c2;
                xh[(D_IN + g) * XH_PAD + r] = h2;
            }
        }
        __syncthreads();
    }

    // ---- write final c ----
    if (tid < H_DIM) {
        #pragma unroll
        for (int r = 0; r < ROWS; ++r) {
            out[(size_t)(row0 + r) * 400 + combo * 100 + tid] = c_lds[r * H_DIM + tid];
        }
    }
}

extern "C" void kernel_launch(void* const* d_in, const int* in_sizes, int n_in,
                              void* d_out, int out_size, void* d_ws, size_t ws_size,
                              hipStream_t stream) {
    const float* premises   = (const float*)d_in[0];
    const float* hypotheses = (const float*)d_in[1];
    const float* Wp_fw = (const float*)d_in[2];
    const float* bp_fw = (const float*)d_in[3];
    const float* Wp_bw = (const float*)d_in[4];
    const float* bp_bw = (const float*)d_in[5];
    const float* Wh_fw = (const float*)d_in[6];
    const float* bh_fw = (const float*)d_in[7];
    const float* Wh_bw = (const float*)d_in[8];
    const float* bh_bw = (const float*)d_in[9];
    float* out = (float*)d_out;

    dim3 grid(1024 / ROWS, 4);   // 64 row-blocks x 4 combos
    dim3 block(BLOCK);
    lstm_fused_f32<<<grid, block, 0, stream>>>(
        premises, hypotheses,
        Wp_fw, bp_fw, Wp_bw, bp_bw,
        Wh_fw, bh_fw, Wh_bw, bh_bw,
        out);
}

// Round 2
// 1212.636 us; speedup vs baseline: 5.8038x; 5.8038x over previous
//
#include <hip/hip_runtime.h>
#include <hip/hip_bf16.h>

#define T_STEPS 128
#define D_IN    300
#define H_DIM   100
#define KDIM    400            // D + H
#define KSTRIDE 424            // padded k stride (848B rows: 16B aligned, bank-friendly)
#define NTILES  25             // 400 gate-cols / 16
#define WAVES   13
#define BLOCK   (WAVES * 64)   // 832
#define MROWS   16             // batch rows per block

typedef __attribute__((ext_vector_type(8))) short bf16x8;
typedef __attribute__((ext_vector_type(4))) float f32x4;

__device__ __forceinline__ ushort f2bf(float f) {
    uint u = __float_as_uint(f);
    u += 0x7FFFu + ((u >> 16) & 1u);     // RNE
    return (ushort)(u >> 16);
}
__device__ __forceinline__ float sigm(float v) {
    return 1.0f / (1.0f + __expf(-v));
}
__device__ __forceinline__ float tanh_(float v) {
    return 2.0f / (1.0f + __expf(-2.0f * v)) - 1.0f;
}
// DPP quad-perm lane swaps (VALU, no LDS traffic)
__device__ __forceinline__ float dpp_xor1(float x) {
    return __int_as_float(__builtin_amdgcn_mov_dpp(__float_as_int(x), 0xB1, 0xF, 0xF, false)); // [1,0,3,2]
}
__device__ __forceinline__ float dpp_xor2(float x) {
    return __int_as_float(__builtin_amdgcn_mov_dpp(__float_as_int(x), 0x4E, 0xF, 0xF, false)); // [2,3,0,1]
}

// ---- Prepass: Wt[combo][p][k] bf16, p = 4*unit + gate (gate-permuted), [n][k] layout ----
__global__ __launch_bounds__(256) void prep_w(
    const float* __restrict__ W0, const float* __restrict__ W1,
    const float* __restrict__ W2, const float* __restrict__ W3,
    ushort* __restrict__ Wt)
{
    int idx = blockIdx.x * 256 + threadIdx.x;
    const int total = 4 * 400 * KSTRIDE;
    if (idx >= total) return;
    int c   = idx / (400 * KSTRIDE);
    int rem = idx - c * (400 * KSTRIDE);
    int p   = rem / KSTRIDE;
    int k   = rem - p * KSTRIDE;
    const float* W = (c == 0) ? W0 : (c == 1) ? W1 : (c == 2) ? W2 : W3;
    float v = 0.0f;
    if (k < KDIM) v = W[k * 400 + (p & 3) * 100 + (p >> 2)];   // gate=(p&3), unit=(p>>2)
    Wt[idx] = f2bf(v);
}

__global__ __launch_bounds__(BLOCK) void lstm_mfma(
    const float* __restrict__ premises,
    const float* __restrict__ hypotheses,
    const float* __restrict__ b0, const float* __restrict__ b1,
    const float* __restrict__ b2, const float* __restrict__ b3,
    const ushort* __restrict__ Wt,
    float* __restrict__ out)
{
    __shared__ ushort xh[2][MROWS * KSTRIDE];   // ping-pong [row][k]: k<300 x, 300..399 h, 400.. zero

    const int tid = threadIdx.x;
    const int l   = tid & 63;
    const int w   = tid >> 6;
    const int combo = blockIdx.y;
    const int row0  = blockIdx.x * MROWS;
    const bool backward = (combo & 1) != 0;
    const float* x    = (combo < 2) ? premises : hypotheses;
    const float* bias = (combo == 0) ? b0 : (combo == 1) ? b1 : (combo == 2) ? b2 : b3;
    const ushort* Wc  = Wt + (size_t)combo * 400 * KSTRIDE;

    // ---- resident B fragments: wave w owns N-tiles {w, w+13} ----
    const int bn = l & 15;            // col within tile
    const int bk = (l >> 4) & 3;      // which 8-elem k-chunk
    const int nt0 = w, nt1 = w + 13;
    bf16x8 bfr0[13], bfr1[13];
    {
        const ushort* bp = Wc + (size_t)(nt0 * 16 + bn) * KSTRIDE + bk * 8;
        #pragma unroll
        for (int ks = 0; ks < 13; ++ks)
            bfr0[ks] = *reinterpret_cast<const bf16x8*>(bp + ks * 32);
    }
    if (nt1 < NTILES) {
        const ushort* bp = Wc + (size_t)(nt1 * 16 + bn) * KSTRIDE + bk * 8;
        #pragma unroll
        for (int ks = 0; ks < 13; ++ks)
            bfr1[ks] = *reinterpret_cast<const bf16x8*>(bp + ks * 32);
    }

    // per-lane bias (gates i,j,f,o of this lane's unit), per tile
    const int ul = (l >> 2) & 3;
    float bi0[4], bi1[4] = {0, 0, 0, 0};
    {
        int u = nt0 * 4 + ul;
        bi0[0] = bias[u]; bi0[1] = bias[100 + u]; bi0[2] = bias[200 + u]; bi0[3] = bias[300 + u];
    }
    if (nt1 < NTILES) {
        int u = nt1 * 4 + ul;
        bi1[0] = bias[u]; bi1[1] = bias[100 + u]; bi1[2] = bias[200 + u]; bi1[3] = bias[300 + u];
    }

    // ---- init LDS: zero k-pad of both buffers, zero h of buf0, stage x_0 ----
    for (int i = tid; i < 2 * MROWS * (KSTRIDE - KDIM); i += BLOCK) {
        int b = i / (MROWS * (KSTRIDE - KDIM));
        int j = i - b * (MROWS * (KSTRIDE - KDIM));
        int r = j / (KSTRIDE - KDIM);
        int k = KDIM + (j - r * (KSTRIDE - KDIM));
        xh[b][r * KSTRIDE + k] = 0;
    }
    for (int i = tid; i < MROWS * H_DIM; i += BLOCK) {
        int r = i / H_DIM;
        xh[0][r * KSTRIDE + D_IN + (i - r * H_DIM)] = 0;
    }
    {
        int t0 = backward ? (T_STEPS - 1) : 0;
        for (int c = tid; c < 1200; c += BLOCK) {
            int r = c / 75, cc = c - (c / 75) * 75;
            float4 v = *reinterpret_cast<const float4*>(
                x + ((size_t)(row0 + r) * T_STEPS + t0) * D_IN + cc * 4);
            ushort4 q;
            q.x = f2bf(v.x); q.y = f2bf(v.y); q.z = f2bf(v.z); q.w = f2bf(v.w);
            *reinterpret_cast<ushort4*>(&xh[0][r * KSTRIDE + cc * 4]) = q;
        }
    }
    __syncthreads();

    // lane roles
    const uint a_off = (uint)(l & 15) * KSTRIDE + (uint)((l >> 4) & 3) * 8;  // A-frag read
    const int  grow  = ((l >> 4) << 2) | (l & 3);                            // gate row (post-transpose)
    const int  sc0 = tid, sc1 = tid + BLOCK;                                 // x-stage chunks
    const int  sr0 = sc0 / 75, sd0 = sc0 - sr0 * 75;
    const int  sr1 = sc1 / 75, sd1 = sc1 - sr1 * 75;
    const bool has1 = (sc1 < 1200);

    float creg0 = 0.0f, creg1 = 0.0f;

    for (int t = 0; t < T_STEPS; ++t) {
        const ushort* cur = &xh[t & 1][0];
        ushort* nxt = &xh[(t & 1) ^ 1][0];

        // prefetch x_{t+1} (global fp32) early — hides HBM under MFMA
        float4 p0, p1;
        if (t < T_STEPS - 1) {
            int tn = backward ? (T_STEPS - 2 - t) : (t + 1);
            p0 = *reinterpret_cast<const float4*>(
                x + ((size_t)(row0 + sr0) * T_STEPS + tn) * D_IN + sd0 * 4);
            if (has1)
                p1 = *reinterpret_cast<const float4*>(
                    x + ((size_t)(row0 + sr1) * T_STEPS + tn) * D_IN + sd1 * 4);
        }

        // A fragments (shared xh tile)
        bf16x8 afr[13];
        #pragma unroll
        for (int ks = 0; ks < 13; ++ks)
            afr[ks] = *reinterpret_cast<const bf16x8*>(cur + a_off + ks * 32);

        // MFMA: z-tiles
        f32x4 acc0 = {0.f, 0.f, 0.f, 0.f}, acc1 = {0.f, 0.f, 0.f, 0.f};
        #pragma unroll
        for (int ks = 0; ks < 13; ++ks)
            acc0 = __builtin_amdgcn_mfma_f32_16x16x32_bf16(afr[ks], bfr0[ks], acc0, 0, 0, 0);
        if (nt1 < NTILES) {
            #pragma unroll
            for (int ks = 0; ks < 13; ++ks)
                acc1 = __builtin_amdgcn_mfma_f32_16x16x32_bf16(afr[ks], bfr1[ks], acc1, 0, 0, 0);
        }

        // per-tile: 4x4 quad transpose (2 DPP stages) -> each lane one (row,unit), gates i,j,f,o
        #pragma unroll
        for (int tt = 0; tt < 2; ++tt) {
            if (tt == 1 && nt1 >= NTILES) continue;
            const f32x4 a = (tt == 0) ? acc0 : acc1;
            const float* bv = (tt == 0) ? bi0 : bi1;
            float v0 = a[0], v1 = a[1], v2 = a[2], v3 = a[3];
            float x20 = dpp_xor2(v0), x21 = dpp_xor2(v1), x22 = dpp_xor2(v2), x23 = dpp_xor2(v3);
            bool h2b = (l & 2) != 0;
            float A0 = h2b ? x22 : v0;
            float A1 = h2b ? x23 : v1;
            float A2 = h2b ? v2 : x20;
            float A3 = h2b ? v3 : x21;
            float y0 = dpp_xor1(A0), y1 = dpp_xor1(A1), y2 = dpp_xor1(A2), y3 = dpp_xor1(A3);
            bool h1b = (l & 1) != 0;
            float zi = (h1b ? y1 : A0) + bv[0];
            float zj = (h1b ? A1 : y0) + bv[1];
            float zf = (h1b ? y3 : A2) + bv[2];
            float zo = (h1b ? A3 : y2) + bv[3];
            float cold = (tt == 0) ? creg0 : creg1;
            float c2 = cold * sigm(zf + 1.0f) + sigm(zi) * tanh_(zj);
            float h2 = tanh_(c2) * sigm(zo);
            if (tt == 0) creg0 = c2; else creg1 = c2;
            int ug = ((tt == 0) ? nt0 : nt1) * 4 + ul;
            nxt[grow * KSTRIDE + D_IN + ug] = f2bf(h2);
        }

        // write staged x_{t+1} into next buffer (bf16)
        if (t < T_STEPS - 1) {
            ushort4 q;
            q.x = f2bf(p0.x); q.y = f2bf(p0.y); q.z = f2bf(p0.z); q.w = f2bf(p0.w);
            *reinterpret_cast<ushort4*>(&nxt[sr0 * KSTRIDE + sd0 * 4]) = q;
            if (has1) {
                q.x = f2bf(p1.x); q.y = f2bf(p1.y); q.z = f2bf(p1.z); q.w = f2bf(p1.w);
                *reinterpret_cast<ushort4*>(&nxt[sr1 * KSTRIDE + sd1 * 4]) = q;
            }
        }
        __syncthreads();
    }

    // ---- final c write ----
    {
        int ug = nt0 * 4 + ul;
        out[(size_t)(row0 + grow) * 400 + combo * 100 + ug] = creg0;
    }
    if (nt1 < NTILES) {
        int ug = nt1 * 4 + ul;
        out[(size_t)(row0 + grow) * 400 + combo * 100 + ug] = creg1;
    }
}

extern "C" void kernel_launch(void* const* d_in, const int* in_sizes, int n_in,
                              void* d_out, int out_size, void* d_ws, size_t ws_size,
                              hipStream_t stream) {
    const float* premises   = (const float*)d_in[0];
    const float* hypotheses = (const float*)d_in[1];
    const float* Wp_fw = (const float*)d_in[2];
    const float* bp_fw = (const float*)d_in[3];
    const float* Wp_bw = (const float*)d_in[4];
    const float* bp_bw = (const float*)d_in[5];
    const float* Wh_fw = (const float*)d_in[6];
    const float* bh_fw = (const float*)d_in[7];
    const float* Wh_bw = (const float*)d_in[8];
    const float* bh_bw = (const float*)d_in[9];
    float* out = (float*)d_out;
    ushort* Wt = (ushort*)d_ws;   // 4*400*424*2 = 1.36 MB

    {
        const int total = 4 * 400 * KSTRIDE;
        prep_w<<<(total + 255) / 256, 256, 0, stream>>>(Wp_fw, Wp_bw, Wh_fw, Wh_bw, Wt);
    }
    dim3 grid(1024 / MROWS, 4);
    lstm_mfma<<<grid, dim3(BLOCK), 0, stream>>>(
        premises, hypotheses,
        bp_fw, bp_bw, bh_fw, bh_bw,
        Wt, out);
}

// Round 3
// 323.058 us; speedup vs baseline: 21.7853x; 3.7536x over previous
//
#include <hip/hip_runtime.h>
#include <hip/hip_bf16.h>

#define T_STEPS 128
#define D_IN    300
#define H_DIM   100
#define KDIM    400            // D + H
#define KSTRIDE 424            // padded k stride in ushorts (848B rows)
#define NTILES  25             // 400 gate-cols / 16
#define WAVES   8
#define BLOCK   (WAVES * 64)   // 512
#define MROWS   16             // batch rows per block
#define NRES    3              // resident N-tiles per wave (8*3=24; tile 24 via LDS on wave 7)

typedef __attribute__((ext_vector_type(8))) short bf16x8;
typedef __attribute__((ext_vector_type(4))) float f32x4;

__device__ __forceinline__ ushort f2bf(float f) {
    uint u = __float_as_uint(f);
    u += 0x7FFFu + ((u >> 16) & 1u);     // RNE
    return (ushort)(u >> 16);
}
__device__ __forceinline__ float sigm(float v) {
    return 1.0f / (1.0f + __expf(-v));
}
__device__ __forceinline__ float tanh_(float v) {
    return 2.0f / (1.0f + __expf(-2.0f * v)) - 1.0f;
}
__device__ __forceinline__ float dpp_xor1(float x) {
    return __int_as_float(__builtin_amdgcn_mov_dpp(__float_as_int(x), 0xB1, 0xF, 0xF, false)); // quad [1,0,3,2]
}
__device__ __forceinline__ float dpp_xor2(float x) {
    return __int_as_float(__builtin_amdgcn_mov_dpp(__float_as_int(x), 0x4E, 0xF, 0xF, false)); // quad [2,3,0,1]
}

// ---- Prepass: Wt[combo][p][k] bf16, p = 4*unit + gate (gate-permuted), [n][k] layout ----
__global__ __launch_bounds__(256) void prep_w(
    const float* __restrict__ W0, const float* __restrict__ W1,
    const float* __restrict__ W2, const float* __restrict__ W3,
    ushort* __restrict__ Wt)
{
    int idx = blockIdx.x * 256 + threadIdx.x;
    const int total = 4 * 400 * KSTRIDE;
    if (idx >= total) return;
    int c   = idx / (400 * KSTRIDE);
    int rem = idx - c * (400 * KSTRIDE);
    int p   = rem / KSTRIDE;
    int k   = rem - p * KSTRIDE;
    const float* W = (c == 0) ? W0 : (c == 1) ? W1 : (c == 2) ? W2 : W3;
    float v = 0.0f;
    if (k < KDIM) v = W[k * 400 + (p & 3) * 100 + (p >> 2)];   // gate=(p&3), unit=(p>>2)
    Wt[idx] = f2bf(v);
}

__global__ __launch_bounds__(BLOCK, 2) void lstm_mfma(
    const float* __restrict__ premises,
    const float* __restrict__ hypotheses,
    const float* __restrict__ b0, const float* __restrict__ b1,
    const float* __restrict__ b2, const float* __restrict__ b3,
    const ushort* __restrict__ Wt,
    float* __restrict__ out)
{
    __shared__ ushort xh[2][MROWS * KSTRIDE];   // ping-pong [row][k]: k<300 x, 300..399 h, 400.. zero
    __shared__ ushort b24[13 * 512];            // tile-24 B frags: [ks][lane] 16B each (13.3 KB)

    const int tid = threadIdx.x;
    const int l   = tid & 63;
    const int w   = tid >> 6;
    const int combo = blockIdx.y;
    const int row0  = blockIdx.x * MROWS;
    const bool backward = (combo & 1) != 0;
    const float* x    = (combo < 2) ? premises : hypotheses;
    const float* bias = (combo == 0) ? b0 : (combo == 1) ? b1 : (combo == 2) ? b2 : b3;
    const ushort* Wc  = Wt + (size_t)combo * 400 * KSTRIDE;

    // ---- B-fragment lane mapping ----
    const int bn = l & 15;            // col within 16-wide tile
    const int bk = (l >> 4) & 3;      // 8-elem k-chunk within 32-k step

    // ---- resident B fragments: wave w owns tiles 3w, 3w+1, 3w+2 ----
    bf16x8 bfr[NRES][13];
    #pragma unroll
    for (int i = 0; i < NRES; ++i) {
        const ushort* bp = Wc + (size_t)((3 * w + i) * 16 + bn) * KSTRIDE + bk * 8;
        #pragma unroll
        for (int ks = 0; ks < 13; ++ks)
            bfr[i][ks] = *reinterpret_cast<const bf16x8*>(bp + ks * 32);
    }
    const bool hasS = (w == WAVES - 1);   // wave 7 also handles tile 24 (from LDS)

    // ---- tile-24 B frags into LDS (frag layout, written once) ----
    if (w == 0) {
        const ushort* bp = Wc + (size_t)(24 * 16 + bn) * KSTRIDE + bk * 8;
        #pragma unroll
        for (int ks = 0; ks < 13; ++ks)
            *reinterpret_cast<bf16x8*>(&b24[ks * 512 + l * 8]) =
                *reinterpret_cast<const bf16x8*>(bp + ks * 32);
    }

    // ---- bias folded into acc init: depends only on C-col = l&15 ----
    // col c of tile nt: unit=(nt*16+c)>>2, gate=c&3; +1.0 for forget gate (c&3==2)
    float bv[NRES], bvS = 0.0f;
    {
        const int c = l & 15;
        const int g = c & 3;
        #pragma unroll
        for (int i = 0; i < NRES; ++i) {
            const int u = ((3 * w + i) * 16 + c) >> 2;
            bv[i] = bias[g * 100 + u] + (g == 2 ? 1.0f : 0.0f);
        }
        if (hasS) {
            const int u = (24 * 16 + c) >> 2;
            bvS = bias[g * 100 + u] + (g == 2 ? 1.0f : 0.0f);
        }
    }

    // ---- init LDS: zero k-pad of both buffers, zero h of buf0, stage x_0 ----
    for (int i = tid; i < 2 * MROWS * (KSTRIDE - KDIM); i += BLOCK) {
        int b = i / (MROWS * (KSTRIDE - KDIM));
        int j = i - b * (MROWS * (KSTRIDE - KDIM));
        int r = j / (KSTRIDE - KDIM);
        int k = KDIM + (j - r * (KSTRIDE - KDIM));
        xh[b][r * KSTRIDE + k] = 0;
    }
    for (int i = tid; i < MROWS * H_DIM; i += BLOCK) {
        int r = i / H_DIM;
        xh[0][r * KSTRIDE + D_IN + (i - r * H_DIM)] = 0;
    }
    {
        int t0 = backward ? (T_STEPS - 1) : 0;
        for (int c = tid; c < 1200; c += BLOCK) {
            int r = c / 75, cc = c - (c / 75) * 75;
            float4 v = *reinterpret_cast<const float4*>(
                x + ((size_t)(row0 + r) * T_STEPS + t0) * D_IN + cc * 4);
            ushort4 q;
            q.x = f2bf(v.x); q.y = f2bf(v.y); q.z = f2bf(v.z); q.w = f2bf(v.w);
            *reinterpret_cast<ushort4*>(&xh[0][r * KSTRIDE + cc * 4]) = q;
        }
    }
    __syncthreads();

    // lane roles
    const uint a_off = (uint)(l & 15) * KSTRIDE + (uint)((l >> 4) & 3) * 8;  // A-frag read (ushort units)
    const int  grow  = ((l >> 4) << 2) | (l & 3);                            // row after quad-transpose
    const int  ul    = (l >> 2) & 3;                                         // unit-within-tile after transpose
    // x-stage assignments: 1200 float4-chunks over 512 threads (<=3 each)
    const int sc0 = tid, sc1 = tid + BLOCK, sc2 = tid + 2 * BLOCK;
    const int sr0 = sc0 / 75, sd0 = sc0 - sr0 * 75;
    const int sr1 = sc1 / 75, sd1 = sc1 - sr1 * 75;
    const int sr2 = sc2 / 75, sd2 = sc2 - sr2 * 75;
    const bool has2 = (sc2 < 1200);

    float creg[NRES] = {0.f, 0.f, 0.f};
    float cregS = 0.f;

    for (int t = 0; t < T_STEPS; ++t) {
        const ushort* cur = &xh[t & 1][0];
        ushort* nxt = &xh[(t & 1) ^ 1][0];

        // prefetch x_{t+1} (global fp32) — hides HBM under MFMA
        float4 p0, p1, p2;
        if (t < T_STEPS - 1) {
            int tn = backward ? (T_STEPS - 2 - t) : (t + 1);
            p0 = *reinterpret_cast<const float4*>(
                x + ((size_t)(row0 + sr0) * T_STEPS + tn) * D_IN + sd0 * 4);
            p1 = *reinterpret_cast<const float4*>(
                x + ((size_t)(row0 + sr1) * T_STEPS + tn) * D_IN + sd1 * 4);
            if (has2)
                p2 = *reinterpret_cast<const float4*>(
                    x + ((size_t)(row0 + sr2) * T_STEPS + tn) * D_IN + sd2 * 4);
        }

        // ---- MFMA: bias-initialized accumulators ----
        f32x4 acc[NRES], accS;
        #pragma unroll
        for (int i = 0; i < NRES; ++i) acc[i] = (f32x4){bv[i], bv[i], bv[i], bv[i]};
        accS = (f32x4){bvS, bvS, bvS, bvS};

        #pragma unroll
        for (int ks = 0; ks < 13; ++ks) {
            const bf16x8 a = *reinterpret_cast<const bf16x8*>(cur + a_off + ks * 32);
            acc[0] = __builtin_amdgcn_mfma_f32_16x16x32_bf16(a, bfr[0][ks], acc[0], 0, 0, 0);
            acc[1] = __builtin_amdgcn_mfma_f32_16x16x32_bf16(a, bfr[1][ks], acc[1], 0, 0, 0);
            acc[2] = __builtin_amdgcn_mfma_f32_16x16x32_bf16(a, bfr[2][ks], acc[2], 0, 0, 0);
            if (hasS) {
                const bf16x8 bs = *reinterpret_cast<const bf16x8*>(&b24[ks * 512 + l * 8]);
                accS = __builtin_amdgcn_mfma_f32_16x16x32_bf16(a, bs, accS, 0, 0, 0);
            }
        }

        // ---- per-tile: quad transpose (DPP) -> lane owns (row=grow, unit=ul), gates i,j,f,o ----
        #pragma unroll
        for (int i = 0; i < NRES + 1; ++i) {
            if (i == NRES && !hasS) break;
            const f32x4 a = (i == NRES) ? accS : acc[i];
            float v0 = a[0], v1 = a[1], v2 = a[2], v3 = a[3];
            float x20 = dpp_xor2(v0), x21 = dpp_xor2(v1), x22 = dpp_xor2(v2), x23 = dpp_xor2(v3);
            bool h2b = (l & 2) != 0;
            float A0 = h2b ? x22 : v0;
            float A1 = h2b ? x23 : v1;
            float A2 = h2b ? v2 : x20;
            float A3 = h2b ? v3 : x21;
            float y0 = dpp_xor1(A0), y1 = dpp_xor1(A1), y2 = dpp_xor1(A2), y3 = dpp_xor1(A3);
            bool h1b = (l & 1) != 0;
            float zi = h1b ? y1 : A0;
            float zj = h1b ? A1 : y0;
            float zf = h1b ? y3 : A2;   // forget bias already folded into acc init
            float zo = h1b ? A3 : y2;
            float cold = (i == NRES) ? cregS : creg[i];
            float c2 = cold * sigm(zf) + sigm(zi) * tanh_(zj);
            float h2 = tanh_(c2) * sigm(zo);
            if (i == NRES) cregS = c2; else creg[i] = c2;
            int ug = ((i == NRES) ? 24 : (3 * w + i)) * 4 + ul;
            nxt[grow * KSTRIDE + D_IN + ug] = f2bf(h2);
        }

        // ---- write staged x_{t+1} into next buffer (bf16) ----
        if (t < T_STEPS - 1) {
            ushort4 q;
            q.x = f2bf(p0.x); q.y = f2bf(p0.y); q.z = f2bf(p0.z); q.w = f2bf(p0.w);
            *reinterpret_cast<ushort4*>(&nxt[sr0 * KSTRIDE + sd0 * 4]) = q;
            q.x = f2bf(p1.x); q.y = f2bf(p1.y); q.z = f2bf(p1.z); q.w = f2bf(p1.w);
            *reinterpret_cast<ushort4*>(&nxt[sr1 * KSTRIDE + sd1 * 4]) = q;
            if (has2) {
                q.x = f2bf(p2.x); q.y = f2bf(p2.y); q.z = f2bf(p2.z); q.w = f2bf(p2.w);
                *reinterpret_cast<ushort4*>(&nxt[sr2 * KSTRIDE + sd2 * 4]) = q;
            }
        }
        __syncthreads();
    }

    // ---- final c write ----
    #pragma unroll
    for (int i = 0; i < NRES; ++i) {
        int ug = (3 * w + i) * 4 + ul;
        out[(size_t)(row0 + grow) * 400 + combo * 100 + ug] = creg[i];
    }
    if (hasS) {
        int ug = 24 * 4 + ul;
        out[(size_t)(row0 + grow) * 400 + combo * 100 + ug] = cregS;
    }
}

extern "C" void kernel_launch(void* const* d_in, const int* in_sizes, int n_in,
                              void* d_out, int out_size, void* d_ws, size_t ws_size,
                              hipStream_t stream) {
    const float* premises   = (const float*)d_in[0];
    const float* hypotheses = (const float*)d_in[1];
    const float* Wp_fw = (const float*)d_in[2];
    const float* bp_fw = (const float*)d_in[3];
    const float* Wp_bw = (const float*)d_in[4];
    const float* bp_bw = (const float*)d_in[5];
    const float* Wh_fw = (const float*)d_in[6];
    const float* bh_fw = (const float*)d_in[7];
    const float* Wh_bw = (const float*)d_in[8];
    const float* bh_bw = (const float*)d_in[9];
    float* out = (float*)d_out;
    ushort* Wt = (ushort*)d_ws;   // 4*400*424*2 = 1.36 MB

    {
        const int total = 4 * 400 * KSTRIDE;
        prep_w<<<(total + 255) / 256, 256, 0, stream>>>(Wp_fw, Wp_bw, Wh_fw, Wh_bw, Wt);
    }
    dim3 grid(1024 / MROWS, 4);
    lstm_mfma<<<grid, dim3(BLOCK), 0, stream>>>(
        premises, hypotheses,
        bp_fw, bp_bw, bh_fw, bh_bw,
        Wt, out);
}

// Round 4
// 215.038 us; speedup vs baseline: 32.7286x; 1.5023x over previous
//
#include <hip/hip_runtime.h>
#include <hip/hip_bf16.h>

#define T_STEPS 128
#define D_IN    300
#define H_DIM   100
#define KDIM    400            // D + H
#define KSTRIDE 424            // padded k stride in ushorts (848B rows)
#define NTILES  25             // 400 gate-cols / 16
#define WAVES   12
#define BLOCK   (WAVES * 64)   // 768
#define MROWS   16             // batch rows per block
#define LN2E    1.44269504f
#define LN2E2   2.88539008f

typedef __attribute__((ext_vector_type(8))) short bf16x8;
typedef __attribute__((ext_vector_type(4))) float f32x4;

__device__ __forceinline__ ushort f2bf(float f) {
    uint u = __float_as_uint(f);
    u += 0x7FFFu + ((u >> 16) & 1u);     // RNE (prepass only)
    return (ushort)(u >> 16);
}
__device__ __forceinline__ uint cvt_pk_bf16(float lo, float hi) {
    uint r;
    asm("v_cvt_pk_bf16_f32 %0, %1, %2" : "=v"(r) : "v"(lo), "v"(hi));
    return r;
}

// Gate math, division-free. z = (zi', zj', zf', zo') pre-scaled by log2(e)
// (2*log2(e) for j), biases (incl. forget bias) folded in. Updates c, returns h.
__device__ __forceinline__ float lstm_gate(const f32x4 z, float& c) {
    float ei = __builtin_amdgcn_exp2f(-z[0]);
    float ej = __builtin_amdgcn_exp2f(fminf(-z[1], 126.0f));   // clamp: (1-ej) path must stay finite
    float ef = __builtin_amdgcn_exp2f(-z[2]);
    float eo = __builtin_amdgcn_exp2f(-z[3]);
    float rf  = __builtin_amdgcn_rcpf(1.0f + ef);               // sigma(f)
    float rij = __builtin_amdgcn_rcpf((1.0f + ei) * (1.0f + ej));
    float c2 = c * rf + (1.0f - ej) * rij;                      // c*sig(f) + sig(i)*tanh(j)
    c = c2;
    float ec = __builtin_amdgcn_exp2f(fminf(-LN2E2 * c2, 126.0f));
    return (1.0f - ec) * __builtin_amdgcn_rcpf((1.0f + ec) * (1.0f + eo)); // tanh(c2)*sig(o)
}

// ---- Prepass: Wt[combo][p][k] bf16, p = 4*unit + gate, [n][k] layout,
// scaled by log2(e) (gate j: 2*log2(e)) so exp2 needs no mul in-kernel ----
__global__ __launch_bounds__(256) void prep_w(
    const float* __restrict__ W0, const float* __restrict__ W1,
    const float* __restrict__ W2, const float* __restrict__ W3,
    ushort* __restrict__ Wt)
{
    int idx = blockIdx.x * 256 + threadIdx.x;
    const int total = 4 * 400 * KSTRIDE;
    if (idx >= total) return;
    int c   = idx / (400 * KSTRIDE);
    int rem = idx - c * (400 * KSTRIDE);
    int p   = rem / KSTRIDE;
    int k   = rem - p * KSTRIDE;
    const float* W = (c == 0) ? W0 : (c == 1) ? W1 : (c == 2) ? W2 : W3;
    const int g = p & 3;
    const float scale = (g == 1) ? LN2E2 : LN2E;
    float v = 0.0f;
    if (k < KDIM) v = W[k * 400 + g * 100 + (p >> 2)] * scale;
    Wt[idx] = f2bf(v);
}

__global__ __launch_bounds__(BLOCK) void lstm_mfma(
    const float* __restrict__ premises,
    const float* __restrict__ hypotheses,
    const float* __restrict__ b0, const float* __restrict__ b1,
    const float* __restrict__ b2, const float* __restrict__ b3,
    const ushort* __restrict__ Wt,
    float* __restrict__ out)
{
    __shared__ ushort xh[2][MROWS * KSTRIDE];   // ping-pong [row][k]: k<300 x, 300..399 h, 400.. zero
    __shared__ ushort b24[13 * 512];            // tile-24 B frags: [ks][lane] 16B each

    const int tid = threadIdx.x;
    const int l   = tid & 63;
    const int w   = tid >> 6;
    const int combo = blockIdx.y;
    const int row0  = blockIdx.x * MROWS;
    const bool backward = (combo & 1) != 0;
    const float* x    = (combo < 2) ? premises : hypotheses;
    const float* bias = (combo == 0) ? b0 : (combo == 1) ? b1 : (combo == 2) ? b2 : b3;
    const ushort* Wc  = Wt + (size_t)combo * 400 * KSTRIDE;

    const int bn = l & 15;            // p within 16-wide tile (W-frag row)
    const int ul = l >> 4;            // k-chunk on load; unit-within-tile on output

    // ---- resident W fragments: wave w owns tiles 2w, 2w+1 ----
    const int nt0 = 2 * w, nt1 = 2 * w + 1;
    bf16x8 bfr0[13], bfr1[13];
    {
        const ushort* bp = Wc + (size_t)(nt0 * 16 + bn) * KSTRIDE + ul * 8;
        #pragma unroll
        for (int ks = 0; ks < 13; ++ks)
            bfr0[ks] = *reinterpret_cast<const bf16x8*>(bp + ks * 32);
    }
    {
        const ushort* bp = Wc + (size_t)(nt1 * 16 + bn) * KSTRIDE + ul * 8;
        #pragma unroll
        for (int ks = 0; ks < 13; ++ks)
            bfr1[ks] = *reinterpret_cast<const bf16x8*>(bp + ks * 32);
    }
    const bool hasS = (w == WAVES - 1);   // wave 11 also handles tile 24 (from LDS)

    if (w == 0) {
        const ushort* bp = Wc + (size_t)(24 * 16 + bn) * KSTRIDE + ul * 8;
        #pragma unroll
        for (int ks = 0; ks < 13; ++ks)
            *reinterpret_cast<bf16x8*>(&b24[ks * 512 + l * 8]) =
                *reinterpret_cast<const bf16x8*>(bp + ks * 32);
    }

    // ---- per-lane bias (acc-init): acc reg j = gate j of unit nt*4+ul ----
    float bva[4], bvb[4], bvS[4] = {0.f, 0.f, 0.f, 0.f};
    {
        int u = nt0 * 4 + ul;
        bva[0] = LN2E * bias[u];
        bva[1] = LN2E2 * bias[100 + u];
        bva[2] = LN2E * (bias[200 + u] + 1.0f);
        bva[3] = LN2E * bias[300 + u];
        u = nt1 * 4 + ul;
        bvb[0] = LN2E * bias[u];
        bvb[1] = LN2E2 * bias[100 + u];
        bvb[2] = LN2E * (bias[200 + u] + 1.0f);
        bvb[3] = LN2E * bias[300 + u];
        if (hasS) {
            u = 96 + ul;
            bvS[0] = LN2E * bias[u];
            bvS[1] = LN2E2 * bias[100 + u];
            bvS[2] = LN2E * (bias[200 + u] + 1.0f);
            bvS[3] = LN2E * bias[300 + u];
        }
    }

    // ---- init LDS: zero k-pads (both buffers), zero h of buf0, stage x_0 ----
    for (int i = tid; i < 2 * MROWS * (KSTRIDE - KDIM); i += BLOCK) {
        int b = i / (MROWS * (KSTRIDE - KDIM));
        int j = i - b * (MROWS * (KSTRIDE - KDIM));
        int r = j / (KSTRIDE - KDIM);
        int k = KDIM + (j - r * (KSTRIDE - KDIM));
        xh[b][r * KSTRIDE + k] = 0;
    }
    for (int i = tid; i < MROWS * H_DIM; i += BLOCK) {
        int r = i / H_DIM;
        xh[0][r * KSTRIDE + D_IN + (i - r * H_DIM)] = 0;
    }
    {
        int t0 = backward ? (T_STEPS - 1) : 0;
        for (int c = tid; c < 1200; c += BLOCK) {
            int r = c / 75, cc = c - (c / 75) * 75;
            float4 v = *reinterpret_cast<const float4*>(
                x + ((size_t)(row0 + r) * T_STEPS + t0) * D_IN + cc * 4);
            uint2 q;
            q.x = cvt_pk_bf16(v.x, v.y);
            q.y = cvt_pk_bf16(v.z, v.w);
            *reinterpret_cast<uint2*>(&xh[0][r * KSTRIDE + cc * 4]) = q;
        }
    }
    __syncthreads();

    // lane roles
    const uint a_off = (uint)(l & 15) * KSTRIDE + (uint)(l >> 4) * 8;  // xh-frag read (ushort units)
    const int  row   = l & 15;                                         // batch row this lane owns (output)
    const int sc0 = tid, sc1 = tid + BLOCK;                            // x-stage chunks
    const int sr0 = sc0 / 75, sd0 = sc0 - sr0 * 75;
    const int sr1 = sc1 / 75, sd1 = sc1 - sr1 * 75;
    const bool has1 = (sc1 < 1200);

    float creg0 = 0.f, creg1 = 0.f, cregS = 0.f;

    for (int t = 0; t < T_STEPS; ++t) {
        const ushort* cur = &xh[t & 1][0];
        ushort* nxt = &xh[(t & 1) ^ 1][0];

        // prefetch x_{t+1} (global fp32) — hides HBM under MFMA
        float4 p0, p1;
        if (t < T_STEPS - 1) {
            int tn = backward ? (T_STEPS - 2 - t) : (t + 1);
            p0 = *reinterpret_cast<const float4*>(
                x + ((size_t)(row0 + sr0) * T_STEPS + tn) * D_IN + sd0 * 4);
            if (has1)
                p1 = *reinterpret_cast<const float4*>(
                    x + ((size_t)(row0 + sr1) * T_STEPS + tn) * D_IN + sd1 * 4);
        }

        // ---- MFMA, W-frag as A-operand: acc[j] = gate j of unit nt*4+ul, col = row ----
        f32x4 acc0 = {bva[0], bva[1], bva[2], bva[3]};
        f32x4 acc1 = {bvb[0], bvb[1], bvb[2], bvb[3]};
        f32x4 accS = {bvS[0], bvS[1], bvS[2], bvS[3]};
        #pragma unroll
        for (int ks = 0; ks < 13; ++ks) {
            const bf16x8 a = *reinterpret_cast<const bf16x8*>(cur + a_off + ks * 32);
            acc0 = __builtin_amdgcn_mfma_f32_16x16x32_bf16(bfr0[ks], a, acc0, 0, 0, 0);
            acc1 = __builtin_amdgcn_mfma_f32_16x16x32_bf16(bfr1[ks], a, acc1, 0, 0, 0);
            if (hasS) {
                const bf16x8 bs = *reinterpret_cast<const bf16x8*>(&b24[ks * 512 + l * 8]);
                accS = __builtin_amdgcn_mfma_f32_16x16x32_bf16(bs, a, accS, 0, 0, 0);
            }
        }

        // ---- gates (no transpose needed) ----
        float h0 = lstm_gate(acc0, creg0);
        float h1 = lstm_gate(acc1, creg1);
        uint pk = cvt_pk_bf16(h0, h1);
        nxt[row * KSTRIDE + D_IN + nt0 * 4 + ul] = (ushort)(pk & 0xFFFFu);
        nxt[row * KSTRIDE + D_IN + nt1 * 4 + ul] = (ushort)(pk >> 16);
        if (hasS) {
            float hS = lstm_gate(accS, cregS);
            nxt[row * KSTRIDE + D_IN + 96 + ul] = (ushort)(cvt_pk_bf16(hS, hS) & 0xFFFFu);
        }

        // ---- write staged x_{t+1} into next buffer (bf16) ----
        if (t < T_STEPS - 1) {
            uint2 q;
            q.x = cvt_pk_bf16(p0.x, p0.y);
            q.y = cvt_pk_bf16(p0.z, p0.w);
            *reinterpret_cast<uint2*>(&nxt[sr0 * KSTRIDE + sd0 * 4]) = q;
            if (has1) {
                q.x = cvt_pk_bf16(p1.x, p1.y);
                q.y = cvt_pk_bf16(p1.z, p1.w);
                *reinterpret_cast<uint2*>(&nxt[sr1 * KSTRIDE + sd1 * 4]) = q;
            }
        }
        __syncthreads();
    }

    // ---- final c write ----
    out[(size_t)(row0 + row) * 400 + combo * 100 + nt0 * 4 + ul] = creg0;
    out[(size_t)(row0 + row) * 400 + combo * 100 + nt1 * 4 + ul] = creg1;
    if (hasS)
        out[(size_t)(row0 + row) * 400 + combo * 100 + 96 + ul] = cregS;
}

extern "C" void kernel_launch(void* const* d_in, const int* in_sizes, int n_in,
                              void* d_out, int out_size, void* d_ws, size_t ws_size,
                              hipStream_t stream) {
    const float* premises   = (const float*)d_in[0];
    const float* hypotheses = (const float*)d_in[1];
    const float* Wp_fw = (const float*)d_in[2];
    const float* bp_fw = (const float*)d_in[3];
    const float* Wp_bw = (const float*)d_in[4];
    const float* bp_bw = (const float*)d_in[5];
    const float* Wh_fw = (const float*)d_in[6];
    const float* bh_fw = (const float*)d_in[7];
    const float* Wh_bw = (const float*)d_in[8];
    const float* bh_bw = (const float*)d_in[9];
    float* out = (float*)d_out;
    ushort* Wt = (ushort*)d_ws;   // 4*400*424*2 = 1.36 MB

    {
        const int total = 4 * 400 * KSTRIDE;
        prep_w<<<(total + 255) / 256, 256, 0, stream>>>(Wp_fw, Wp_bw, Wh_fw, Wh_bw, Wt);
    }
    dim3 grid(1024 / MROWS, 4);
    lstm_mfma<<<grid, dim3(BLOCK), 0, stream>>>(
        premises, hypotheses,
        bp_fw, bp_bw, bh_fw, bh_bw,
        Wt, out);
}